// Round 1
// baseline (128.880 us; speedup 1.0000x reference)
//
#include <hip/hip_runtime.h>

// DataTermLayer: per-pixel optical-flow data-term update.
// Inputs (float32, each B*H*W = 16*1024*1024):
//   d_in[0]=I1, d_in[1]=I2, d_in[2]=u, d_in[3]=v
// Output: d_out = [u_next (N floats) | v_next (N floats)]
//
// Faithful-to-reference detail: the Python source assigns
//   I1_grad_x, I1_grad_y = _image_gradients(I1)
// but _image_gradients returns (dy, dx). So grad_x := dy (vertical diff),
// grad_y := dx (horizontal diff).

#define ALPHA 0.15f
#define IMG_H 1024
#define IMG_W 1024

__global__ __launch_bounds__(256) void dataterm_kernel(
        const float* __restrict__ I1,
        const float* __restrict__ I2,
        const float* __restrict__ u,
        const float* __restrict__ v,
        float* __restrict__ out_u,
        float* __restrict__ out_v,
        int total) {
    int idx = blockIdx.x * blockDim.x + threadIdx.x;
    if (idx >= total) return;

    const int W = IMG_W, H = IMG_H;
    int w = idx & (W - 1);
    int h = (idx >> 10) & (H - 1);
    int b = idx >> 20;

    const float* __restrict__ I1b = I1 + (size_t)b * (size_t)(H * W);

    // --- image gradients (dy, dx) with zero last row/col ---
    float c   = I1b[h * W + w];
    float gdy = (h < H - 1) ? (I1b[(h + 1) * W + w] - c) : 0.0f;  // "grad_x" in ref
    float gdx = (w < W - 1) ? (I1b[h * W + (w + 1)] - c) : 0.0f;  // "grad_y" in ref

    // --- bilinear warp of I1 at (w + 0.5u, h + 0.5v), zero padding ---
    float uu = u[idx];
    float vv = v[idx];
    float x = (float)w + 0.5f * uu;
    float y = (float)h + 0.5f * vv;

    float x0f = floorf(x);
    float y0f = floorf(y);
    float wx1 = x - x0f;
    float wx0 = 1.0f - wx1;
    float wy1 = y - y0f;
    float wy0 = 1.0f - wy1;

    int x0 = (int)x0f;
    int y0 = (int)y0f;
    int x1 = x0 + 1;
    int y1 = y0 + 1;

    float vx0 = (x0 >= 0 && x0 <= W - 1) ? 1.0f : 0.0f;
    float vx1 = (x1 >= 0 && x1 <= W - 1) ? 1.0f : 0.0f;
    float vy0 = (y0 >= 0 && y0 <= H - 1) ? 1.0f : 0.0f;
    float vy1 = (y1 >= 0 && y1 <= H - 1) ? 1.0f : 0.0f;

    int x0c = min(max(x0, 0), W - 1);
    int x1c = min(max(x1, 0), W - 1);
    int y0c = min(max(y0, 0), H - 1);
    int y1c = min(max(y1, 0), H - 1);

    // Reference gathers at clipped indices then multiplies by validity.
    float g00 = I1b[y0c * W + x0c] * (vy0 * vx0);
    float g01 = I1b[y0c * W + x1c] * (vy0 * vx1);
    float g10 = I1b[y1c * W + x0c] * (vy1 * vx0);
    float g11 = I1b[y1c * W + x1c] * (vy1 * vx1);

    float warped = g00 * (wy0 * wx0)
                 + g01 * (wy0 * wx1)
                 + g10 * (wy1 * wx0)
                 + g11 * (wy1 * wx1);

    float dataTerm = warped - I2[idx];

    out_u[idx] = uu - ALPHA * dataTerm * gdy;
    out_v[idx] = vv - ALPHA * dataTerm * gdx;
}

extern "C" void kernel_launch(void* const* d_in, const int* in_sizes, int n_in,
                              void* d_out, int out_size, void* d_ws, size_t ws_size,
                              hipStream_t stream) {
    const float* I1 = (const float*)d_in[0];
    const float* I2 = (const float*)d_in[1];
    const float* u  = (const float*)d_in[2];
    const float* v  = (const float*)d_in[3];

    int total = in_sizes[0];               // B*H*W = 16 * 1024 * 1024
    float* out_u = (float*)d_out;          // first half
    float* out_v = (float*)d_out + total;  // second half

    int block = 256;
    int grid = (total + block - 1) / block;
    dataterm_kernel<<<grid, block, 0, stream>>>(I1, I2, u, v, out_u, out_v, total);
}

// Round 3
// 97.698 us; speedup vs baseline: 1.3192x; 1.3192x over previous
//
#include <hip/hip_runtime.h>

// DataTermLayer: per-pixel optical-flow data-term update.
// Inputs (float32, each B*H*W = 16*1024*1024):
//   d_in[0]=I1, d_in[1]=I2, d_in[2]=u, d_in[3]=v
// Output: d_out = [u_next (N floats) | v_next (N floats)]
//
// Faithful-to-reference: grad_x := dy (vertical diff), grad_y := dx
// (horizontal diff) — the Python source swaps them.
//
// R3: 4 pixels/thread via native 4-wide float vectors (16 B/lane streaming
// loads/stores, 4 independent bilinear-gather chains per thread for MLP),
// non-temporal output stores (ext_vector_type — HIP float4 is rejected by
// the builtin) to keep I1 resident in L2/L3.

#define ALPHA 0.15f
#define IMG_H 1024
#define IMG_W 1024

typedef float f32x4 __attribute__((ext_vector_type(4)));

__global__ __launch_bounds__(256) void dataterm_kernel(
        const float* __restrict__ I1,
        const float* __restrict__ I2,
        const float* __restrict__ u,
        const float* __restrict__ v,
        float* __restrict__ out_u,
        float* __restrict__ out_v,
        int total4) {
    int t = blockIdx.x * blockDim.x + threadIdx.x;
    if (t >= total4) return;
    int p = t << 2;  // first pixel of this thread's group of 4

    const int W = IMG_W, H = IMG_H;
    int w = p & (W - 1);          // w in {0,4,...,1020}
    int h = (p >> 10) & (H - 1);
    int b = p >> 20;

    const float* __restrict__ I1b = I1 + (size_t)b * (size_t)(H * W);
    const float* rowc = I1b + h * W + w;

    // --- streaming loads (16 B/lane) ---
    f32x4 c4 = *(const f32x4*)rowc;
    // element W-neighbor of lane's last pixel (w+4); guard row end
    bool lastcol = (w + 4 > W - 1);
    float c4r = lastcol ? 0.0f : rowc[4];
    // next row (for dy); dy = 0 on last row -> reuse c4 so diff is 0
    f32x4 d4 = (h < H - 1) ? *(const f32x4*)(rowc + W) : c4;

    f32x4 u4  = *(const f32x4*)(u + p);
    f32x4 v4  = *(const f32x4*)(v + p);
    f32x4 i24 = *(const f32x4*)(I2 + p);

    // gradients: gy = vertical diff (ref "grad_x", scales u-update)
    //            gx = horizontal diff (ref "grad_y", scales v-update)
    float gy[4] = { d4.x - c4.x, d4.y - c4.y, d4.z - c4.z, d4.w - c4.w };
    float gx[4] = { c4.y - c4.x, c4.z - c4.y, c4.w - c4.z,
                    lastcol ? 0.0f : (c4r - c4.w) };

    float uu[4] = { u4.x, u4.y, u4.z, u4.w };
    float vv[4] = { v4.x, v4.y, v4.z, v4.w };
    float i2[4] = { i24.x, i24.y, i24.z, i24.w };
    float ru[4], rv[4];

    #pragma unroll
    for (int i = 0; i < 4; ++i) {
        float x = (float)(w + i) + 0.5f * uu[i];
        float y = (float)h       + 0.5f * vv[i];

        float x0f = floorf(x);
        float y0f = floorf(y);
        float wx1 = x - x0f;
        float wx0 = 1.0f - wx1;
        float wy1 = y - y0f;
        float wy0 = 1.0f - wy1;

        int x0 = (int)x0f, y0 = (int)y0f;
        int x1 = x0 + 1,   y1 = y0 + 1;

        float vx0 = (x0 >= 0 && x0 <= W - 1) ? 1.0f : 0.0f;
        float vx1 = (x1 >= 0 && x1 <= W - 1) ? 1.0f : 0.0f;
        float vy0 = (y0 >= 0 && y0 <= H - 1) ? 1.0f : 0.0f;
        float vy1 = (y1 >= 0 && y1 <= H - 1) ? 1.0f : 0.0f;

        int x0c = min(max(x0, 0), W - 1);
        int x1c = min(max(x1, 0), W - 1);
        int y0c = min(max(y0, 0), H - 1);
        int y1c = min(max(y1, 0), H - 1);

        float g00 = I1b[y0c * W + x0c] * (vy0 * vx0);
        float g01 = I1b[y0c * W + x1c] * (vy0 * vx1);
        float g10 = I1b[y1c * W + x0c] * (vy1 * vx0);
        float g11 = I1b[y1c * W + x1c] * (vy1 * vx1);

        float warped = g00 * (wy0 * wx0)
                     + g01 * (wy0 * wx1)
                     + g10 * (wy1 * wx0)
                     + g11 * (wy1 * wx1);

        float dataTerm = warped - i2[i];
        ru[i] = uu[i] - ALPHA * dataTerm * gy[i];
        rv[i] = vv[i] - ALPHA * dataTerm * gx[i];
    }

    f32x4 ruv = { ru[0], ru[1], ru[2], ru[3] };
    f32x4 rvv = { rv[0], rv[1], rv[2], rv[3] };
    __builtin_nontemporal_store(ruv, (f32x4*)(out_u + p));
    __builtin_nontemporal_store(rvv, (f32x4*)(out_v + p));
}

extern "C" void kernel_launch(void* const* d_in, const int* in_sizes, int n_in,
                              void* d_out, int out_size, void* d_ws, size_t ws_size,
                              hipStream_t stream) {
    const float* I1 = (const float*)d_in[0];
    const float* I2 = (const float*)d_in[1];
    const float* u  = (const float*)d_in[2];
    const float* v  = (const float*)d_in[3];

    int total = in_sizes[0];               // B*H*W = 16 * 1024 * 1024
    int total4 = total >> 2;               // 4 pixels per thread
    float* out_u = (float*)d_out;
    float* out_v = (float*)d_out + total;

    int block = 256;
    int grid = (total4 + block - 1) / block;
    dataterm_kernel<<<grid, block, 0, stream>>>(I1, I2, u, v, out_u, out_v, total4);
}

// Round 4
// 91.816 us; speedup vs baseline: 1.4037x; 1.0641x over previous
//
#include <hip/hip_runtime.h>

// DataTermLayer: per-pixel optical-flow data-term update.
// Inputs (float32, each B*H*W = 16*1024*1024):
//   d_in[0]=I1, d_in[1]=I2, d_in[2]=u, d_in[3]=v
// Output: d_out = [u_next (N floats) | v_next (N floats)]
//
// Faithful-to-reference: grad_x := dy (vertical diff), grad_y := dx
// (horizontal diff) — the Python source swaps them.
//
// R4: halve the bilinear-gather address stream. In the common case
// (0 <= x0 <= W-2, implying both columns valid), fetch each corner row
// pair with ONE 8B f32x2 load at column x0 (gfx950 unaligned access mode
// handles 4B-aligned dwordx2). 16 -> 8 gather instructions per thread.
// Border samples (<1%) take the scalar 4-load fallback (also avoids any
// OOB tail read).

#define ALPHA 0.15f
#define IMG_H 1024
#define IMG_W 1024

typedef float f32x4 __attribute__((ext_vector_type(4)));
typedef float f32x2 __attribute__((ext_vector_type(2)));

__global__ __launch_bounds__(256) void dataterm_kernel(
        const float* __restrict__ I1,
        const float* __restrict__ I2,
        const float* __restrict__ u,
        const float* __restrict__ v,
        float* __restrict__ out_u,
        float* __restrict__ out_v,
        int total4) {
    int t = blockIdx.x * blockDim.x + threadIdx.x;
    if (t >= total4) return;
    int p = t << 2;  // first pixel of this thread's group of 4

    const int W = IMG_W, H = IMG_H;
    int w = p & (W - 1);          // w in {0,4,...,1020}
    int h = (p >> 10) & (H - 1);
    int b = p >> 20;

    const float* __restrict__ I1b = I1 + (size_t)b * (size_t)(H * W);
    const float* rowc = I1b + h * W + w;

    // --- streaming loads (16 B/lane) ---
    f32x4 c4 = *(const f32x4*)rowc;
    bool lastcol = (w + 4 > W - 1);
    float c4r = lastcol ? 0.0f : rowc[4];
    f32x4 d4 = (h < H - 1) ? *(const f32x4*)(rowc + W) : c4;

    f32x4 u4  = *(const f32x4*)(u + p);
    f32x4 v4  = *(const f32x4*)(v + p);
    f32x4 i24 = *(const f32x4*)(I2 + p);

    // gradients: gy = vertical diff (ref "grad_x", scales u-update)
    //            gx = horizontal diff (ref "grad_y", scales v-update)
    float gy[4] = { d4.x - c4.x, d4.y - c4.y, d4.z - c4.z, d4.w - c4.w };
    float gx[4] = { c4.y - c4.x, c4.z - c4.y, c4.w - c4.z,
                    lastcol ? 0.0f : (c4r - c4.w) };

    float uu[4] = { u4.x, u4.y, u4.z, u4.w };
    float vv[4] = { v4.x, v4.y, v4.z, v4.w };
    float i2[4] = { i24.x, i24.y, i24.z, i24.w };
    float ru[4], rv[4];

    #pragma unroll
    for (int i = 0; i < 4; ++i) {
        float x = (float)(w + i) + 0.5f * uu[i];
        float y = (float)h       + 0.5f * vv[i];

        float x0f = floorf(x);
        float y0f = floorf(y);
        float wx1 = x - x0f;
        float wx0 = 1.0f - wx1;
        float wy1 = y - y0f;
        float wy0 = 1.0f - wy1;

        int x0 = (int)x0f, y0 = (int)y0f;
        int y1 = y0 + 1;

        float vy0 = (y0 >= 0 && y0 <= H - 1) ? 1.0f : 0.0f;
        float vy1 = (y1 >= 0 && y1 <= H - 1) ? 1.0f : 0.0f;
        int y0c = min(max(y0, 0), H - 1);
        int y1c = min(max(y1, 0), H - 1);

        float g00, g01, g10, g11;
        if (__builtin_expect(x0 >= 0 && x0 <= W - 2, 1)) {
            // common case: x0,x1 both in-image (vx0=vx1=1); one 8B load per row
            f32x2 q0 = *(const f32x2*)(I1b + y0c * W + x0);
            f32x2 q1 = *(const f32x2*)(I1b + y1c * W + x0);
            g00 = q0.x * vy0;
            g01 = q0.y * vy0;
            g10 = q1.x * vy1;
            g11 = q1.y * vy1;
        } else {
            int x1 = x0 + 1;
            float vx0 = (x0 >= 0 && x0 <= W - 1) ? 1.0f : 0.0f;
            float vx1 = (x1 >= 0 && x1 <= W - 1) ? 1.0f : 0.0f;
            int x0c = min(max(x0, 0), W - 1);
            int x1c = min(max(x1, 0), W - 1);
            g00 = I1b[y0c * W + x0c] * (vy0 * vx0);
            g01 = I1b[y0c * W + x1c] * (vy0 * vx1);
            g10 = I1b[y1c * W + x0c] * (vy1 * vx0);
            g11 = I1b[y1c * W + x1c] * (vy1 * vx1);
        }

        float warped = g00 * (wy0 * wx0)
                     + g01 * (wy0 * wx1)
                     + g10 * (wy1 * wx0)
                     + g11 * (wy1 * wx1);

        float dataTerm = warped - i2[i];
        ru[i] = uu[i] - ALPHA * dataTerm * gy[i];
        rv[i] = vv[i] - ALPHA * dataTerm * gx[i];
    }

    f32x4 ruv = { ru[0], ru[1], ru[2], ru[3] };
    f32x4 rvv = { rv[0], rv[1], rv[2], rv[3] };
    __builtin_nontemporal_store(ruv, (f32x4*)(out_u + p));
    __builtin_nontemporal_store(rvv, (f32x4*)(out_v + p));
}

extern "C" void kernel_launch(void* const* d_in, const int* in_sizes, int n_in,
                              void* d_out, int out_size, void* d_ws, size_t ws_size,
                              hipStream_t stream) {
    const float* I1 = (const float*)d_in[0];
    const float* I2 = (const float*)d_in[1];
    const float* u  = (const float*)d_in[2];
    const float* v  = (const float*)d_in[3];

    int total = in_sizes[0];               // B*H*W = 16 * 1024 * 1024
    int total4 = total >> 2;               // 4 pixels per thread
    float* out_u = (float*)d_out;
    float* out_v = (float*)d_out + total;

    int block = 256;
    int grid = (total4 + block - 1) / block;
    dataterm_kernel<<<grid, block, 0, stream>>>(I1, I2, u, v, out_u, out_v, total4);
}

// Round 5
// 70.713 us; speedup vs baseline: 1.8226x; 1.2984x over previous
//
#include <hip/hip_runtime.h>

// DataTermLayer: per-pixel optical-flow data-term update.
// Inputs (float32, each B*H*W = 16*1024*1024):
//   d_in[0]=I1, d_in[1]=I2, d_in[2]=u, d_in[3]=v
// Output: d_out = [u_next (N floats) | v_next (N floats)]
//
// Faithful-to-reference: grad_x := dy (vertical diff), grad_y := dx
// (horizontal diff) — the Python source swaps them.
//
// R5: LDS-staged I1 tile. The R4 limiter was the divergent bilinear
// gathers: per-pixel random row offsets mean ~1 L1 cache-line transaction
// per lane per gather (~500 lines/wave) serializing in the TA/L1 while
// VALU (15%) and HBM (33%) idle. Stage a 128x8 tile + 4/5-px halo in LDS
// (9.3 KB) with clamped fill, gather from LDS instead. Clamped fill also
// makes last-row/col zero-gradients automatic, and gradients read from
// LDS (drops the c4/d4 streaming loads). Displacements are 0.5*N(0,1)
// (|u|max ~5.5 over 16M) so the halo covers all samples; a (never-taken,
// exec-skipped) global fallback keeps correctness for arbitrary inputs.

#define ALPHA 0.15f
#define IMG_H 1024
#define IMG_W 1024
#define TW 128
#define TH 8
#define HALO 4
#define LW (TW + 9)   // 137: halo 4 left, 5 right (x1 = x0+1)
#define LH (TH + 9)   // 17:  halo 4 up,   5 down  (y1 = y0+1)

typedef float f32x4 __attribute__((ext_vector_type(4)));

__global__ __launch_bounds__(256) void dataterm_kernel(
        const float* __restrict__ I1,
        const float* __restrict__ I2,
        const float* __restrict__ u,
        const float* __restrict__ v,
        float* __restrict__ out_u,
        float* __restrict__ out_v) {
    const int W = IMG_W, H = IMG_H;
    const int t   = threadIdx.x;
    const int tx0 = blockIdx.x * TW;
    const int ty0 = blockIdx.y * TH;
    const int b   = blockIdx.z;

    const float* __restrict__ I1b = I1 + (size_t)b * (size_t)(H * W);

    __shared__ float S[LH * LW];

    // --- cooperative clamped tile fill (coalesced within rows) ---
    for (int f = t; f < LH * LW; f += 256) {
        int ly = f / LW;
        int lx = f - ly * LW;
        int gy = min(max(ty0 - HALO + ly, 0), H - 1);
        int gx = min(max(tx0 - HALO + lx, 0), W - 1);
        S[f] = I1b[gy * W + gx];
    }
    __syncthreads();

    // thread -> 4 consecutive pixels of one row
    const int r  = t >> 5;           // row within tile, 0..7
    const int cb = (t & 31) << 2;    // col base within tile, 0..124
    const int h  = ty0 + r;
    const int wb = tx0 + cb;
    const int p  = (b * H + h) * W + wb;

    f32x4 u4  = *(const f32x4*)(u + p);
    f32x4 v4  = *(const f32x4*)(v + p);
    f32x4 i24 = *(const f32x4*)(I2 + p);

    float uu[4] = { u4.x, u4.y, u4.z, u4.w };
    float vv[4] = { v4.x, v4.y, v4.z, v4.w };
    float i2[4] = { i24.x, i24.y, i24.z, i24.w };
    float ru[4], rv[4];

    const int cl = (HALO + r) * LW + HALO + cb;  // LDS index of pixel (h, wb)

    #pragma unroll
    for (int i = 0; i < 4; ++i) {
        // gradients from LDS; clamped fill zeroes them at image edges
        float c     = S[cl + i];
        float right = S[cl + i + 1];
        float down  = S[cl + i + LW];
        float gxv = right - c;  // ref "grad_y" (horizontal), scales v-update
        float gyv = down - c;   // ref "grad_x" (vertical),   scales u-update

        float x = (float)(wb + i) + 0.5f * uu[i];
        float y = (float)h        + 0.5f * vv[i];

        float x0f = floorf(x);
        float y0f = floorf(y);
        float wx1 = x - x0f;
        float wx0 = 1.0f - wx1;
        float wy1 = y - y0f;
        float wy0 = 1.0f - wy1;

        int x0 = (int)x0f, y0 = (int)y0f;
        int x1 = x0 + 1,   y1 = y0 + 1;

        float vx0 = (x0 >= 0 && x0 <= W - 1) ? 1.0f : 0.0f;
        float vx1 = (x1 >= 0 && x1 <= W - 1) ? 1.0f : 0.0f;
        float vy0 = (y0 >= 0 && y0 <= H - 1) ? 1.0f : 0.0f;
        float vy1 = (y1 >= 0 && y1 <= H - 1) ? 1.0f : 0.0f;

        int lx0 = x0 - tx0 + HALO;
        int ly0 = y0 - ty0 + HALO;

        float g00, g01, g10, g11;
        if ((unsigned)lx0 <= (unsigned)(LW - 2) &&
            (unsigned)ly0 <= (unsigned)(LH - 2)) {
            // in-tile (the always case): gather from LDS
            int q = ly0 * LW + lx0;
            g00 = S[q]          * (vy0 * vx0);
            g01 = S[q + 1]      * (vy0 * vx1);
            g10 = S[q + LW]     * (vy1 * vx0);
            g11 = S[q + LW + 1] * (vy1 * vx1);
        } else {
            // out-of-halo fallback (never taken for N(0,1) flow): global
            int x0c = min(max(x0, 0), W - 1);
            int x1c = min(max(x1, 0), W - 1);
            int y0c = min(max(y0, 0), H - 1);
            int y1c = min(max(y1, 0), H - 1);
            g00 = I1b[y0c * W + x0c] * (vy0 * vx0);
            g01 = I1b[y0c * W + x1c] * (vy0 * vx1);
            g10 = I1b[y1c * W + x0c] * (vy1 * vx0);
            g11 = I1b[y1c * W + x1c] * (vy1 * vx1);
        }

        float warped = g00 * (wy0 * wx0)
                     + g01 * (wy0 * wx1)
                     + g10 * (wy1 * wx0)
                     + g11 * (wy1 * wx1);

        float dataTerm = warped - i2[i];
        ru[i] = uu[i] - ALPHA * dataTerm * gyv;
        rv[i] = vv[i] - ALPHA * dataTerm * gxv;
    }

    f32x4 ruv = { ru[0], ru[1], ru[2], ru[3] };
    f32x4 rvv = { rv[0], rv[1], rv[2], rv[3] };
    __builtin_nontemporal_store(ruv, (f32x4*)(out_u + p));
    __builtin_nontemporal_store(rvv, (f32x4*)(out_v + p));
}

extern "C" void kernel_launch(void* const* d_in, const int* in_sizes, int n_in,
                              void* d_out, int out_size, void* d_ws, size_t ws_size,
                              hipStream_t stream) {
    const float* I1 = (const float*)d_in[0];
    const float* I2 = (const float*)d_in[1];
    const float* u  = (const float*)d_in[2];
    const float* v  = (const float*)d_in[3];

    int total = in_sizes[0];               // B*H*W = 16 * 1024 * 1024
    float* out_u = (float*)d_out;
    float* out_v = (float*)d_out + total;

    dim3 grid(IMG_W / TW, IMG_H / TH, total / (IMG_H * IMG_W));
    dataterm_kernel<<<grid, dim3(256), 0, stream>>>(I1, I2, u, v, out_u, out_v);
}